// Round 15
// baseline (134.589 us; speedup 1.0000x reference)
//
#include <hip/hip_runtime.h>
#include <math.h>

#ifndef __has_builtin
#define __has_builtin(x) 0
#endif

#define NPTS   131072
#define FCH    16
#define CSND   343.0f
#define PB     16           // points per pass
#define BLOCK  256          // 4 waves
#define GRID   512          // 2 WG/CU * 256 CUs, persistent (16 passes/WG)
#define NBLK   (NPTS / PB)  // 8192

// LDS dword offsets (total 10240 dw = 40 KB):
//   bufA[k] = k*3072   (48 rows x 64 dw: t rows 0-15, s rows 16-31, c1 32-47)
//   bufHG[k]= 6144 + k*2048 (16 x 128 dw)
#define AOFF(k)  ((k) * 3072)
#define HOFF(k)  (6144 + (k) * 2048)

typedef _Float16 half8 __attribute__((ext_vector_type(8)));
typedef _Float16 half2v __attribute__((ext_vector_type(2)));
typedef float    f32x4 __attribute__((ext_vector_type(4)));

static __device__ __forceinline__ half2v pk2h(float a, float b) {
#if __has_builtin(__builtin_amdgcn_cvt_pkrtz)
  return __builtin_bit_cast(half2v, __builtin_amdgcn_cvt_pkrtz(a, b));
#else
  half2v v; v[0] = (_Float16)a; v[1] = (_Float16)b;
  return v;
#endif
}
static __device__ __forceinline__ unsigned pack2(float a, float b) {
  return __builtin_bit_cast(unsigned, pk2h(a, b));
}
#define U32(h) __builtin_bit_cast(unsigned, (h))

// tanh(x) = 1 - 2/(e^{2x}+1): exp+rcp on trans pipe, monotone at +/-inf.
static __device__ __forceinline__ float mytanh(float x) {
#if __has_builtin(__builtin_amdgcn_exp2f)
  float e = __builtin_amdgcn_exp2f(2.885390082f * x);   // 2*log2(e)*x
#else
  float e = __expf(2.0f * x);
#endif
  return fmaf(-2.0f, __builtin_amdgcn_rcpf(e + 1.0f), 1.0f);
}

// R14 LDS-TRAFFIC REDUCTION, register file UN-SABOTAGED. R14's failure was
// the ALLOCATOR, not the theory: at (256,2) it targeted 128 VGPRs (its own
// occupancy heuristic, not the 256 cap) and spilled the w2fd sets -- WRITE
// 23.6MB, 70.8us. Fix: __launch_bounds__(256,1) -> cap 512, heuristic stops
// chasing occupancy, allocator takes the ~200-230 the body needs, zero spill.
// Hardware residency follows ACTUAL VGPR: <=256 -> 2 waves/EU = 2 WG/CU,
// identical to R9. Single token changed vs R14.
// Theory under test (R14, unmeasured due to spills): R9 is LDS-pipe-bound
// (~25 b128/lane-pass ~= 20-25us chip-wide > VALU ~16us > MFMA ~8.5us).
// Exact algebra (s.w_d)@W2 = s@(diag(w_d)W2): 3 STATIC pre-scaled W2
// fragment sets w2fd[d] replace the 3 materialized directional A-matrices.
// A writes {t,s,c1} (3 b128 vs 5); B1 reads s-fragment ONCE per ks for all
// 3 direction GEMMs (12 frag reads vs 20). Per lane-pass: 25 -> 15 b128.
// Loop: [A(i+1)->bufA[!c] || D(i-1) rd HG[!c] || B(i) rd bufA[c]; C(i)->HG[c]]
// |bar|. Hazards parity-ordered (R9). Phases/tiling byte-for-byte R9.

__global__ __launch_bounds__(BLOCK, 1) void helmholtz_kernel(
    const float* __restrict__ x,      // [N,3]
    const float* __restrict__ omega,  // [16]
    const float* __restrict__ W1,     // [3,128]
    const float* __restrict__ b1,     // [128]
    const float* __restrict__ W2,     // [128,128]
    const float* __restrict__ b2,     // [128]
    const float* __restrict__ W3,     // [128,32]
    const float* __restrict__ b3,     // [32]
    float* __restrict__ out)
{
  __shared__ unsigned s_mem[10240];   // 40 KB: 2x bufA(12KB) + 2x bufHG(8KB)

  // ---- one-time half-pass stagger: de-convoy the 2 WGs sharing each CU ----
  if ((blockIdx.x >> 8) & 1) {
#pragma unroll
    for (int i = 0; i < 3; i++) __builtin_amdgcn_s_sleep(48);
  }

  const int tid  = threadIdx.x;
  const int w    = tid >> 6;   // wave 0..3
  const int l    = tid & 63;
  const int col  = l & 15;
  const int quad = l >> 4;
  const int nh   = w & 1;      // D re/im tile (waves 0/1)

  // ---- phase A task: point pA (one per thread); units 8g..8g+7 ----
  const int pA = tid >> 4;     // 0..15
  const int g  = tid & 15;
  float wx[8], wy[8], wz[8], bB[8];
#pragma unroll
  for (int u = 0; u < 8; u++) {
    int unit = 8 * g + u;
    wx[u] = W1[unit]; wy[u] = W1[128 + unit]; wz[u] = W1[256 + unit];
    bB[u] = b1[unit];
  }
  // folded -2*|w|^2 for the c1 pack (computed once)
  half2v wqm[4];
#pragma unroll
  for (int j = 0; j < 4; j++) {
    float wq0 = fmaf(wx[2*j],   wx[2*j],   fmaf(wy[2*j],   wy[2*j],   wz[2*j]   * wz[2*j]));
    float wq1 = fmaf(wx[2*j+1], wx[2*j+1], fmaf(wy[2*j+1], wy[2*j+1], wz[2*j+1] * wz[2*j+1]));
    wqm[j] = pk2h(-2.0f * wq0, -2.0f * wq1);
  }
  const half2v hone = {(_Float16)1.0f, (_Float16)1.0f};

  // ---- W2^T fragments (plain, for h/c1 GEMMs): cols 32*w+16*nt+col ----
  half8 w2f[2][4];
#pragma unroll
  for (int nt = 0; nt < 2; nt++) {
    const int n = 32 * w + 16 * nt + col;
#pragma unroll
    for (int ks = 0; ks < 4; ks++) {
      half8 f;
#pragma unroll
      for (int j8 = 0; j8 < 8; j8++)
        f[j8] = (_Float16)W2[(ks * 32 + (quad << 3) + j8) * 128 + n];
      w2f[nt][ks] = f;
    }
  }
  // ---- pre-scaled W2 sets: w2fd[d] = diag(W1_d) * W2 fragments (static) ----
  half8 w2fd[3][2][4];
#pragma unroll
  for (int d = 0; d < 3; d++)
#pragma unroll
    for (int nt = 0; nt < 2; nt++) {
      const int n = 32 * w + 16 * nt + col;
#pragma unroll
      for (int ks = 0; ks < 4; ks++) {
        half8 f;
#pragma unroll
        for (int j8 = 0; j8 < 8; j8++) {
          int k = ks * 32 + (quad << 3) + j8;
          f[j8] = (_Float16)(W1[128 * d + k] * W2[k * 128 + n]);
        }
        w2fd[d][nt][ks] = f;
      }
    }
  // ---- W3^T fragment, j-permuted to match HG layout (16 VGPRs) ----
  half8 w3f[4];
#pragma unroll
  for (int ks = 0; ks < 4; ks++) {
    half8 f;
#pragma unroll
    for (int j8 = 0; j8 < 8; j8++) {
      int j = 32 * ks + 16 * (j8 & 1) + 4 * quad + (j8 >> 1);
      f[j8] = (_Float16)W3[j * 32 + 16 * nh + col];
    }
    w3f[ks] = f;
  }

  float b2r[2];
#pragma unroll
  for (int nt = 0; nt < 2; nt++) b2r[nt] = b2[32 * w + 16 * nt + col];
  float k2v = 0.0f;
  if (col >= 1) {
    float om = omega[col] * (1.0f / CSND);
    k2v = om * om;
  }
  const float b3v = b3[16 * nh + col];

  float wsum = 0.0f;
  float xrC[3], xrN[3];

  auto loadX = [&](int blk, float* xr) {
    const float* xb = x + (size_t)blk * PB * 3;
    xr[0] = xb[3 * pA]; xr[1] = xb[3 * pA + 1]; xr[2] = xb[3 * pA + 2];
  };

  // A: writes only {t, s, c1} (3 b128/lane)
  auto phaseA = [&](int aOff, const float* xr) {
    const int cbase = ((g ^ pA) << 2) + aOff;
    float x0 = xr[0], x1 = xr[1], x2 = xr[2];
    float t[8];
#pragma unroll
    for (int u = 0; u < 8; u++) {
      float z = fmaf(x0, wx[u], fmaf(x1, wy[u], fmaf(x2, wz[u], bB[u])));
      t[u] = mytanh(z);
    }
    half2v tp[4], sp[4], cp[4];
#pragma unroll
    for (int j = 0; j < 4; j++) {
      tp[j] = pk2h(t[2*j], t[2*j+1]);
      sp[j] = hone - tp[j] * tp[j];
      cp[j] = (tp[j] * sp[j]) * wqm[j];
    }
    uint4 q;
    q = make_uint4(U32(tp[0]), U32(tp[1]), U32(tp[2]), U32(tp[3]));
    *(uint4*)&s_mem[(pA)      * 64 + cbase] = q;
    q = make_uint4(U32(sp[0]), U32(sp[1]), U32(sp[2]), U32(sp[3]));
    *(uint4*)&s_mem[(16 + pA) * 64 + cbase] = q;
    q = make_uint4(U32(cp[0]), U32(cp[1]), U32(cp[2]), U32(cp[3]));
    *(uint4*)&s_mem[(32 + pA) * 64 + cbase] = q;
  };

  auto phaseD = [&](int hOff) {
    if (w < 2) {
      const int pbase = hOff + col * 128;   // row = col; swizzle key col
      f32x4 dy = (f32x4){0.0f, 0.0f, 0.0f, 0.0f};
      f32x4 dl = (f32x4){0.0f, 0.0f, 0.0f, 0.0f};
#pragma unroll
      for (int ks = 0; ks < 4; ks++) {
        int pos = ((((ks << 2) + quad) ^ col) << 2);
        half8 afy = *(const half8*)&s_mem[pbase + pos];
        half8 afl = *(const half8*)&s_mem[pbase + 64 + pos];
        dy = __builtin_amdgcn_mfma_f32_16x16x32_f16(afy, w3f[ks], dy, 0, 0, 0);
        dl = __builtin_amdgcn_mfma_f32_16x16x32_f16(afl, w3f[ks], dl, 0, 0, 0);
      }
      if (col >= 1) {
#pragma unroll
        for (int r = 0; r < 4; r++) {
          float yv  = dy[r] + b3v;
          float res = fmaf(k2v, yv, dl[r]);
          wsum += res * res;
        }
      }
    }
  };

  // ---- prologue: A(first pass) + x prefetch ----
  loadX(blockIdx.x, xrC);
  phaseA(AOFF(0), xrC);
  {
    int nb = blockIdx.x + GRID;
    if (nb < NBLK) loadX(nb, xrN);
  }
  __syncthreads();

  bool hasPrev = false;
  int cur = 0;
  for (int blk = blockIdx.x; blk < NBLK; blk += GRID) {
    int nblk = blk + GRID;
    // ---- A(i+1) -> bufA[cur^1]  (independent of B/C/D this region) ----
    if (nblk < NBLK) {
      xrC[0] = xrN[0]; xrC[1] = xrN[1]; xrC[2] = xrN[2];
      int n2 = nblk + GRID;
      if (n2 < NBLK) loadX(n2, xrN);
      phaseA(AOFF(cur ^ 1), xrC);
    }
    // ---- D(i-1): reads bufHG[cur^1]  (independent) ----
    if (hasPrev) phaseD(HOFF(cur ^ 1));

    const int aOff = AOFF(cur);
    // ---- B1: direction GEMMs via pre-scaled W2 sets; s-frag read ONCE/ks --
    f32x4 bsum[2];
    {
      f32x4 accd[3][2];
#pragma unroll
      for (int d = 0; d < 3; d++)
#pragma unroll
        for (int nt = 0; nt < 2; nt++)
          accd[d][nt] = (f32x4){0.0f, 0.0f, 0.0f, 0.0f};
      const int rbs = aOff + (16 + col) * 64;     // s rows (v=1)
#pragma unroll
      for (int ks = 0; ks < 4; ks++) {
        half8 afs = *(const half8*)&s_mem[rbs + ((((ks << 2) + quad) ^ col) << 2)];
        accd[0][0] = __builtin_amdgcn_mfma_f32_16x16x32_f16(afs, w2fd[0][0][ks], accd[0][0], 0, 0, 0);
        accd[0][1] = __builtin_amdgcn_mfma_f32_16x16x32_f16(afs, w2fd[0][1][ks], accd[0][1], 0, 0, 0);
        accd[1][0] = __builtin_amdgcn_mfma_f32_16x16x32_f16(afs, w2fd[1][0][ks], accd[1][0], 0, 0, 0);
        accd[1][1] = __builtin_amdgcn_mfma_f32_16x16x32_f16(afs, w2fd[1][1][ks], accd[1][1], 0, 0, 0);
        accd[2][0] = __builtin_amdgcn_mfma_f32_16x16x32_f16(afs, w2fd[2][0][ks], accd[2][0], 0, 0, 0);
        accd[2][1] = __builtin_amdgcn_mfma_f32_16x16x32_f16(afs, w2fd[2][1][ks], accd[2][1], 0, 0, 0);
      }
#pragma unroll
      for (int nt = 0; nt < 2; nt++)
        bsum[nt] = accd[0][nt] * accd[0][nt] + accd[1][nt] * accd[1][nt]
                 + accd[2][nt] * accd[2][nt];
    }
    // ---- B2: h-GEMM (t) and c1-GEMM via plain w2f ----
    f32x4 acch[2], accc[2];
#pragma unroll
    for (int nt = 0; nt < 2; nt++) {
      acch[nt] = (f32x4){0.0f, 0.0f, 0.0f, 0.0f};
      accc[nt] = (f32x4){0.0f, 0.0f, 0.0f, 0.0f};
    }
    {
      const int rbt = aOff + (col) * 64;          // t rows (v=0)
      const int rbc = aOff + (32 + col) * 64;     // c1 rows (v=2)
#pragma unroll
      for (int ks = 0; ks < 4; ks++) {
        int pos = ((((ks << 2) + quad) ^ col) << 2);
        half8 aft = *(const half8*)&s_mem[rbt + pos];
        half8 afc = *(const half8*)&s_mem[rbc + pos];
        acch[0] = __builtin_amdgcn_mfma_f32_16x16x32_f16(aft, w2f[0][ks], acch[0], 0, 0, 0);
        acch[1] = __builtin_amdgcn_mfma_f32_16x16x32_f16(aft, w2f[1][ks], acch[1], 0, 0, 0);
        accc[0] = __builtin_amdgcn_mfma_f32_16x16x32_f16(afc, w2f[0][ks], accc[0], 0, 0, 0);
        accc[1] = __builtin_amdgcn_mfma_f32_16x16x32_f16(afc, w2f[1][ks], accc[1], 0, 0, 0);
      }
    }

    // ---- C(i): layer-2 elementwise -> bufHG[cur] (q = 16w+col) ----
    {
      const int hOff = HOFF(cur);
      const int q    = 16 * w + col;
      const int qc   = q >> 2, qr = q & 3;
#pragma unroll
      for (int r = 0; r < 4; r++) {
        int p = (quad << 2) + r;             // point 0..15
        float t2[2], gg[2];
#pragma unroll
        for (int nt = 0; nt < 2; nt++) {
          float z2 = acch[nt][r] + b2r[nt];
          float t  = mytanh(z2);
          float s2 = 1.0f - t * t;
          t2[nt] = t;
          gg[nt] = s2 * (accc[nt][r] - 2.0f * t * bsum[nt][r]);
        }
        int pos = ((qc ^ p) << 2) + qr;
        int pb  = hOff + p * 128;
        s_mem[pb + pos]      = pack2(t2[0], t2[1]);
        s_mem[pb + 64 + pos] = pack2(gg[0], gg[1]);
      }
    }

    hasPrev = true;
    __syncthreads();               // single barrier per pass
    cur ^= 1;
  }
  phaseD(HOFF(cur ^ 1));           // epilogue D (last C wrote bufHG[cur^1])

  // ---- final: wave reduce, one atomic per wave ----
#pragma unroll
  for (int off = 32; off > 0; off >>= 1)
    wsum += __shfl_down(wsum, off, 64);
  if (l == 0)
    atomicAdd(out, wsum * (1.0f / ((float)NPTS * (float)(FCH - 1))));
}

extern "C" void kernel_launch(void* const* d_in, const int* in_sizes, int n_in,
                              void* d_out, int out_size, void* d_ws, size_t ws_size,
                              hipStream_t stream) {
  const float* x     = (const float*)d_in[0];
  const float* omega = (const float*)d_in[1];
  const float* W1    = (const float*)d_in[2];
  const float* b1    = (const float*)d_in[3];
  const float* W2    = (const float*)d_in[4];
  const float* b2    = (const float*)d_in[5];
  const float* W3    = (const float*)d_in[6];
  const float* b3    = (const float*)d_in[7];
  float* out = (float*)d_out;

  (void)hipMemsetAsync(out, 0, sizeof(float), stream);
  helmholtz_kernel<<<GRID, BLOCK, 0, stream>>>(x, omega, W1, b1, W2, b2, W3, b3, out);
}

// Round 16
// 117.428 us; speedup vs baseline: 1.1461x; 1.1461x over previous
//
#include <hip/hip_runtime.h>
#include <math.h>

#ifndef __has_builtin
#define __has_builtin(x) 0
#endif

#define NPTS   131072
#define FCH    16
#define CSND   343.0f
#define PB     16           // points per pass
#define BLOCK  256          // 4 waves
#define GRID   512          // 2 WG/CU * 256 CUs, persistent (16 passes/WG)
#define NBLK   (NPTS / PB)  // 8192

// LDS dword offsets (total 14336 dw = 56 KB -> 2 WG/CU):
//   bufA[k]  = k*5120        (80 rows x 64 dw, k=0/1)
//   bufHG[k] = 10240 + k*2048 (16 x 128 dw,    k=0/1)
#define AOFF(k)  ((k) * 5120)
#define HOFF(k)  (10240 + (k) * 2048)

typedef _Float16 half8 __attribute__((ext_vector_type(8)));
typedef _Float16 half2v __attribute__((ext_vector_type(2)));
typedef float    f32x4 __attribute__((ext_vector_type(4)));

static __device__ __forceinline__ half2v pk2h(float a, float b) {
#if __has_builtin(__builtin_amdgcn_cvt_pkrtz)
  return __builtin_bit_cast(half2v, __builtin_amdgcn_cvt_pkrtz(a, b));
#else
  half2v v; v[0] = (_Float16)a; v[1] = (_Float16)b;
  return v;
#endif
}
static __device__ __forceinline__ unsigned pack2(float a, float b) {
  return __builtin_bit_cast(unsigned, pk2h(a, b));
}
#define U32(h) __builtin_bit_cast(unsigned, (h))

// tanh(x) = 1 - 2/(e^{2x}+1): exp+rcp on trans pipe, monotone at +/-inf.
static __device__ __forceinline__ float mytanh(float x) {
#if __has_builtin(__builtin_amdgcn_exp2f)
  float e = __builtin_amdgcn_exp2f(2.885390082f * x);   // 2*log2(e)*x
#else
  float e = __expf(2.0f * x);
#endif
  return fmaf(-2.0f, __builtin_amdgcn_rcpf(e + 1.0f), 1.0f);
}

// R9 EXACT BASE (best measured: 56.5us, VGPR=100, clean) + two ILP deltas.
// R15 refuted the LDS-pipe theory (-40% LDS traffic -> 73.7us, WORSE): R9 is
// DEPENDENCY-LATENCY-bound (~1.3k cyc issue/wave-pass vs 8.5k elapsed; 2
// waves/SIMD can't fill ds_read ~120cy + serialized-MFMA gaps). Only ILP wins
// have ever worked this session (R6 packing, R9 pipelining). Deltas:
//  1) B1+B2 MERGED into ONE ks-loop, accd un-collapsed to [3][2]: 10
//     independent MFMA chains (3d x 2nt + t x 2 + c1 x 2) instead of R9's
//     3 serialized 2-chain blocks (accd register reuse forced d-block
//     ordering, ~400cy exposed latency/wave-pass). All 5 ds_read streams
//     issue per ks. +16 VGPR (est ~116 <= 128: allocator's 4-wave target
//     still fits -- the R14 spill mode needs ~200).
//  2) T5 s_setprio(1) around B's MFMA cluster and D's MFMAs: the 2 WGs are
//     phase-staggered -> role diversity for the CU scheduler to arbitrate.
// Everything else byte-for-byte R9: 1-barrier pipelined loop, dbuf parity,
// phases A/C/D, tiling n=32w+16nt+col, stagger, 56KB LDS, (256,2).
// Loop: [A(i+1)->bufA[!c] || D(i-1) rd HG[!c] || B(i)+C(i)] |bar|.

__global__ __launch_bounds__(BLOCK, 2) void helmholtz_kernel(
    const float* __restrict__ x,      // [N,3]
    const float* __restrict__ omega,  // [16]
    const float* __restrict__ W1,     // [3,128]
    const float* __restrict__ b1,     // [128]
    const float* __restrict__ W2,     // [128,128]
    const float* __restrict__ b2,     // [128]
    const float* __restrict__ W3,     // [128,32]
    const float* __restrict__ b3,     // [32]
    float* __restrict__ out)
{
  __shared__ unsigned s_mem[14336];   // 56 KB: 2x bufA + 2x bufHG

  // ---- one-time half-pass stagger: de-convoy the 2 WGs sharing each CU ----
  if ((blockIdx.x >> 8) & 1) {
#pragma unroll
    for (int i = 0; i < 3; i++) __builtin_amdgcn_s_sleep(48);
  }

  const int tid  = threadIdx.x;
  const int w    = tid >> 6;   // wave 0..3
  const int l    = tid & 63;
  const int col  = l & 15;
  const int quad = l >> 4;
  const int nh   = w & 1;      // D re/im tile (waves 0/1)

  // ---- phase A task: point pA (one per thread); units 8g..8g+7 ----
  const int pA = tid >> 4;     // 0..15
  const int g  = tid & 15;
  float wx[8], wy[8], wz[8], bB[8];
#pragma unroll
  for (int u = 0; u < 8; u++) {
    int unit = 8 * g + u;
    wx[u] = W1[unit]; wy[u] = W1[128 + unit]; wz[u] = W1[256 + unit];
    bB[u] = b1[unit];
  }
  // packed W1 copies + folded -2*wq (computed once)
  half2v wxp[4], wyp[4], wzp[4], wqm[4];
#pragma unroll
  for (int j = 0; j < 4; j++) {
    wxp[j] = pk2h(wx[2*j], wx[2*j+1]);
    wyp[j] = pk2h(wy[2*j], wy[2*j+1]);
    wzp[j] = pk2h(wz[2*j], wz[2*j+1]);
    float wq0 = fmaf(wx[2*j],   wx[2*j],   fmaf(wy[2*j],   wy[2*j],   wz[2*j]   * wz[2*j]));
    float wq1 = fmaf(wx[2*j+1], wx[2*j+1], fmaf(wy[2*j+1], wy[2*j+1], wz[2*j+1] * wz[2*j+1]));
    wqm[j] = pk2h(-2.0f * wq0, -2.0f * wq1);
  }
  const half2v hone = {(_Float16)1.0f, (_Float16)1.0f};

  // ---- W2^T fragments: 2 n-tiles (cols 32*w + 16*nt + col), 32 VGPRs ----
  half8 w2f[2][4];
#pragma unroll
  for (int nt = 0; nt < 2; nt++) {
    const int n = 32 * w + 16 * nt + col;
#pragma unroll
    for (int ks = 0; ks < 4; ks++) {
      half8 f;
#pragma unroll
      for (int j8 = 0; j8 < 8; j8++)
        f[j8] = (_Float16)W2[(ks * 32 + (quad << 3) + j8) * 128 + n];
      w2f[nt][ks] = f;
    }
  }
  // ---- W3^T fragment, j-permuted to match HG layout (16 VGPRs) ----
  half8 w3f[4];
#pragma unroll
  for (int ks = 0; ks < 4; ks++) {
    half8 f;
#pragma unroll
    for (int j8 = 0; j8 < 8; j8++) {
      int j = 32 * ks + 16 * (j8 & 1) + 4 * quad + (j8 >> 1);
      f[j8] = (_Float16)W3[j * 32 + 16 * nh + col];
    }
    w3f[ks] = f;
  }

  float b2r[2];
#pragma unroll
  for (int nt = 0; nt < 2; nt++) b2r[nt] = b2[32 * w + 16 * nt + col];
  float k2v = 0.0f;
  if (col >= 1) {
    float om = omega[col] * (1.0f / CSND);
    k2v = om * om;
  }
  const float b3v = b3[16 * nh + col];

  float wsum = 0.0f;
  float xrC[3], xrN[3];

  auto loadX = [&](int blk, float* xr) {
    const float* xb = x + (size_t)blk * PB * 3;
    xr[0] = xb[3 * pA]; xr[1] = xb[3 * pA + 1]; xr[2] = xb[3 * pA + 2];
  };

  auto phaseA = [&](int aOff, const float* xr) {
    const int cbase = ((g ^ pA) << 2) + aOff;
    float x0 = xr[0], x1 = xr[1], x2 = xr[2];
    float t[8];
#pragma unroll
    for (int u = 0; u < 8; u++) {
      float z = fmaf(x0, wx[u], fmaf(x1, wy[u], fmaf(x2, wz[u], bB[u])));
      t[u] = mytanh(z);
    }
    half2v tp[4], sp[4];
#pragma unroll
    for (int j = 0; j < 4; j++) {
      tp[j] = pk2h(t[2*j], t[2*j+1]);
      sp[j] = hone - tp[j] * tp[j];
    }
    uint4 q;
    q = make_uint4(U32(tp[0]), U32(tp[1]), U32(tp[2]), U32(tp[3]));
    *(uint4*)&s_mem[(pA)      * 64 + cbase] = q;
    q = make_uint4(U32(sp[0]*wxp[0]), U32(sp[1]*wxp[1]),
                   U32(sp[2]*wxp[2]), U32(sp[3]*wxp[3]));
    *(uint4*)&s_mem[(16 + pA) * 64 + cbase] = q;
    q = make_uint4(U32(sp[0]*wyp[0]), U32(sp[1]*wyp[1]),
                   U32(sp[2]*wyp[2]), U32(sp[3]*wyp[3]));
    *(uint4*)&s_mem[(32 + pA) * 64 + cbase] = q;
    q = make_uint4(U32(sp[0]*wzp[0]), U32(sp[1]*wzp[1]),
                   U32(sp[2]*wzp[2]), U32(sp[3]*wzp[3]));
    *(uint4*)&s_mem[(48 + pA) * 64 + cbase] = q;
    half2v cp[4];
#pragma unroll
    for (int j = 0; j < 4; j++) cp[j] = (tp[j] * sp[j]) * wqm[j];
    q = make_uint4(U32(cp[0]), U32(cp[1]), U32(cp[2]), U32(cp[3]));
    *(uint4*)&s_mem[(64 + pA) * 64 + cbase] = q;
  };

  auto phaseD = [&](int hOff) {
    if (w < 2) {
      const int pbase = hOff + col * 128;   // row = col; swizzle key col
      f32x4 dy = (f32x4){0.0f, 0.0f, 0.0f, 0.0f};
      f32x4 dl = (f32x4){0.0f, 0.0f, 0.0f, 0.0f};
      __builtin_amdgcn_s_setprio(1);
#pragma unroll
      for (int ks = 0; ks < 4; ks++) {
        int pos = ((((ks << 2) + quad) ^ col) << 2);
        half8 afy = *(const half8*)&s_mem[pbase + pos];
        half8 afl = *(const half8*)&s_mem[pbase + 64 + pos];
        dy = __builtin_amdgcn_mfma_f32_16x16x32_f16(afy, w3f[ks], dy, 0, 0, 0);
        dl = __builtin_amdgcn_mfma_f32_16x16x32_f16(afl, w3f[ks], dl, 0, 0, 0);
      }
      __builtin_amdgcn_s_setprio(0);
      if (col >= 1) {
#pragma unroll
        for (int r = 0; r < 4; r++) {
          float yv  = dy[r] + b3v;
          float res = fmaf(k2v, yv, dl[r]);
          wsum += res * res;
        }
      }
    }
  };

  // ---- prologue: A(first pass) + x prefetch ----
  loadX(blockIdx.x, xrC);
  phaseA(AOFF(0), xrC);
  {
    int nb = blockIdx.x + GRID;
    if (nb < NBLK) loadX(nb, xrN);
  }
  __syncthreads();

  bool hasPrev = false;
  int cur = 0;
  for (int blk = blockIdx.x; blk < NBLK; blk += GRID) {
    int nblk = blk + GRID;
    // ---- A(i+1) -> bufA[cur^1]  (independent of B/C/D this region) ----
    if (nblk < NBLK) {
      xrC[0] = xrN[0]; xrC[1] = xrN[1]; xrC[2] = xrN[2];
      int n2 = nblk + GRID;
      if (n2 < NBLK) loadX(n2, xrN);
      phaseA(AOFF(cur ^ 1), xrC);
    }
    // ---- D(i-1): reads bufHG[cur^1]  (independent) ----
    if (hasPrev) phaseD(HOFF(cur ^ 1));

    // ---- B(i): MERGED GEMM, 10 independent accumulator chains ----
    const int aOff = AOFF(cur);
    f32x4 accd[3][2], acch[2], accc[2];
#pragma unroll
    for (int d = 0; d < 3; d++)
#pragma unroll
      for (int nt = 0; nt < 2; nt++)
        accd[d][nt] = (f32x4){0.0f, 0.0f, 0.0f, 0.0f};
#pragma unroll
    for (int nt = 0; nt < 2; nt++) {
      acch[nt] = (f32x4){0.0f, 0.0f, 0.0f, 0.0f};
      accc[nt] = (f32x4){0.0f, 0.0f, 0.0f, 0.0f};
    }
    {
      const int rbt = aOff + (col) * 64;        // t  rows (v=0)
      const int rb0 = aOff + (16 + col) * 64;   // d0 rows (v=1)
      const int rb1 = aOff + (32 + col) * 64;   // d1 rows (v=2)
      const int rb2 = aOff + (48 + col) * 64;   // d2 rows (v=3)
      const int rbc = aOff + (64 + col) * 64;   // c1 rows (v=4)
      __builtin_amdgcn_s_setprio(1);
#pragma unroll
      for (int ks = 0; ks < 4; ks++) {
        int pos = ((((ks << 2) + quad) ^ col) << 2);
        half8 aft = *(const half8*)&s_mem[rbt + pos];
        half8 af0 = *(const half8*)&s_mem[rb0 + pos];
        half8 af1 = *(const half8*)&s_mem[rb1 + pos];
        half8 af2 = *(const half8*)&s_mem[rb2 + pos];
        half8 afc = *(const half8*)&s_mem[rbc + pos];
        acch[0]    = __builtin_amdgcn_mfma_f32_16x16x32_f16(aft, w2f[0][ks], acch[0],    0, 0, 0);
        acch[1]    = __builtin_amdgcn_mfma_f32_16x16x32_f16(aft, w2f[1][ks], acch[1],    0, 0, 0);
        accd[0][0] = __builtin_amdgcn_mfma_f32_16x16x32_f16(af0, w2f[0][ks], accd[0][0], 0, 0, 0);
        accd[0][1] = __builtin_amdgcn_mfma_f32_16x16x32_f16(af0, w2f[1][ks], accd[0][1], 0, 0, 0);
        accd[1][0] = __builtin_amdgcn_mfma_f32_16x16x32_f16(af1, w2f[0][ks], accd[1][0], 0, 0, 0);
        accd[1][1] = __builtin_amdgcn_mfma_f32_16x16x32_f16(af1, w2f[1][ks], accd[1][1], 0, 0, 0);
        accd[2][0] = __builtin_amdgcn_mfma_f32_16x16x32_f16(af2, w2f[0][ks], accd[2][0], 0, 0, 0);
        accd[2][1] = __builtin_amdgcn_mfma_f32_16x16x32_f16(af2, w2f[1][ks], accd[2][1], 0, 0, 0);
        accc[0]    = __builtin_amdgcn_mfma_f32_16x16x32_f16(afc, w2f[0][ks], accc[0],    0, 0, 0);
        accc[1]    = __builtin_amdgcn_mfma_f32_16x16x32_f16(afc, w2f[1][ks], accc[1],    0, 0, 0);
      }
      __builtin_amdgcn_s_setprio(0);
    }
    f32x4 bsum[2];
#pragma unroll
    for (int nt = 0; nt < 2; nt++)
      bsum[nt] = accd[0][nt] * accd[0][nt] + accd[1][nt] * accd[1][nt]
               + accd[2][nt] * accd[2][nt];

    // ---- C(i): layer-2 elementwise -> bufHG[cur] (q = 16w+col) ----
    {
      const int hOff = HOFF(cur);
      const int q    = 16 * w + col;
      const int qc   = q >> 2, qr = q & 3;
#pragma unroll
      for (int r = 0; r < 4; r++) {
        int p = (quad << 2) + r;             // point 0..15
        float t2[2], gg[2];
#pragma unroll
        for (int nt = 0; nt < 2; nt++) {
          float z2 = acch[nt][r] + b2r[nt];
          float t  = mytanh(z2);
          float s2 = 1.0f - t * t;
          t2[nt] = t;
          gg[nt] = s2 * (accc[nt][r] - 2.0f * t * bsum[nt][r]);
        }
        int pos = ((qc ^ p) << 2) + qr;
        int pb  = hOff + p * 128;
        s_mem[pb + pos]      = pack2(t2[0], t2[1]);
        s_mem[pb + 64 + pos] = pack2(gg[0], gg[1]);
      }
    }

    hasPrev = true;
    __syncthreads();               // single barrier per pass
    cur ^= 1;
  }
  phaseD(HOFF(cur ^ 1));           // epilogue D (last C wrote bufHG[cur^1])

  // ---- final: wave reduce, one atomic per wave ----
#pragma unroll
  for (int off = 32; off > 0; off >>= 1)
    wsum += __shfl_down(wsum, off, 64);
  if (l == 0)
    atomicAdd(out, wsum * (1.0f / ((float)NPTS * (float)(FCH - 1))));
}

extern "C" void kernel_launch(void* const* d_in, const int* in_sizes, int n_in,
                              void* d_out, int out_size, void* d_ws, size_t ws_size,
                              hipStream_t stream) {
  const float* x     = (const float*)d_in[0];
  const float* omega = (const float*)d_in[1];
  const float* W1    = (const float*)d_in[2];
  const float* b1    = (const float*)d_in[3];
  const float* W2    = (const float*)d_in[4];
  const float* b2    = (const float*)d_in[5];
  const float* W3    = (const float*)d_in[6];
  const float* b3    = (const float*)d_in[7];
  float* out = (float*)d_out;

  (void)hipMemsetAsync(out, 0, sizeof(float), stream);
  helmholtz_kernel<<<GRID, BLOCK, 0, stream>>>(x, omega, W1, b1, W2, b2, W3, b3, out);
}